// Round 1
// baseline (422.934 us; speedup 1.0000x reference)
//
#include <hip/hip_runtime.h>

#define NPOS 6272          // 8*28*28
#define NT   98            // NPOS/64
#define CIN  256
#define CR   32
#define BATCH 2
#define LOG2E 1.4426950408889634f
#define QSCALE 0.17677669529663689f  // 1/sqrt(32)

// ---------------------------------------------------------------------------
// Kernel 1: Q/K/V projections.
// Q layout [B][32][N]  (coalesced per-lane column reads in attention)
// K,V layout [B][N][32] (contiguous 128B per key row -> uniform scalar loads)
// Block = 256 threads = 4 waves; wave g handles r in [8g, 8g+8).
// ---------------------------------------------------------------------------
__global__ __launch_bounds__(256) void qkv_kernel(
    const float* __restrict__ x, const float* __restrict__ qw,
    const float* __restrict__ kw, const float* __restrict__ vw,
    float* __restrict__ Q, float* __restrict__ K, float* __restrict__ V)
{
    const int b  = blockIdx.y;
    const int nl = threadIdx.x & 63;
    const int n  = blockIdx.x * 64 + nl;
    const int g  = __builtin_amdgcn_readfirstlane(threadIdx.x >> 6); // wave-uniform 0..3
    const float* xb = x + (size_t)b * CIN * NPOS + n;

    float aq[8], ak[8], av[8];
#pragma unroll
    for (int i = 0; i < 8; ++i) { aq[i] = 0.f; ak[i] = 0.f; av[i] = 0.f; }

    for (int c = 0; c < CIN; ++c) {
        float xv = xb[(size_t)c * NPOS];
#pragma unroll
        for (int i = 0; i < 8; ++i) {
            int r = g * 8 + i;                   // wave-uniform -> scalar weight loads
            aq[i] += qw[r * CIN + c] * xv;
            ak[i] += kw[r * CIN + c] * xv;
            av[i] += vw[r * CIN + c] * xv;
        }
    }
#pragma unroll
    for (int i = 0; i < 8; ++i) {
        int r = g * 8 + i;
        Q[((size_t)b * CR + r) * NPOS + n] = aq[i] * QSCALE;  // fold softmax scale into Q
        K[((size_t)b * NPOS + n) * CR + r] = ak[i];
        V[((size_t)b * NPOS + n) * CR + r] = av[i];
    }
}

// ---------------------------------------------------------------------------
// Kernel 2: flash attention with key-split.
// 1 block = 1 wave = 64 queries; blockIdx.y = key split s; blockIdx.z = batch.
// Online softmax over this split's key range; partial (m, l, o[32]) to ws.
// K/V rows are wave-uniform -> scalar (SMEM) loads, dual-issue with VALU.
// ---------------------------------------------------------------------------
__global__ __launch_bounds__(64) void attn_kernel(
    const float* __restrict__ Q, const float* __restrict__ K,
    const float* __restrict__ V, float* __restrict__ Opart,
    float* __restrict__ Mpart, float* __restrict__ Lpart, int kps)
{
    const int b = blockIdx.z;
    const int s = blockIdx.y;
    const int n = blockIdx.x * 64 + threadIdx.x;

    const float* Qb = Q + (size_t)b * CR * NPOS + n;
    const float* Kb = K + (size_t)b * NPOS * CR;
    const float* Vb = V + (size_t)b * NPOS * CR;

    float q[CR];
#pragma unroll
    for (int r = 0; r < CR; ++r) q[r] = Qb[(size_t)r * NPOS];
    float o[CR];
#pragma unroll
    for (int r = 0; r < CR; ++r) o[r] = 0.f;
    float m = -1e30f, l = 0.f;

    const int j0 = s * kps;
    for (int jc = 0; jc < kps; jc += 8) {
        float sc[8];
#pragma unroll
        for (int jj = 0; jj < 8; ++jj) {
            const float* kr = Kb + (size_t)(j0 + jc + jj) * CR;  // uniform row
            float a0 = 0.f, a1 = 0.f, a2 = 0.f, a3 = 0.f;
#pragma unroll
            for (int r = 0; r < CR; r += 4) {
                a0 += q[r]     * kr[r];
                a1 += q[r + 1] * kr[r + 1];
                a2 += q[r + 2] * kr[r + 2];
                a3 += q[r + 3] * kr[r + 3];
            }
            sc[jj] = (a0 + a1) + (a2 + a3);
        }
        float cm = sc[0];
#pragma unroll
        for (int jj = 1; jj < 8; ++jj) cm = fmaxf(cm, sc[jj]);
        float mn    = fmaxf(m, cm);
        float alpha = __builtin_amdgcn_exp2f((m - mn) * LOG2E);
        l *= alpha;
#pragma unroll
        for (int r = 0; r < CR; ++r) o[r] *= alpha;
#pragma unroll
        for (int jj = 0; jj < 8; ++jj) {
            float p = __builtin_amdgcn_exp2f((sc[jj] - mn) * LOG2E);
            l += p;
            const float* vr = Vb + (size_t)(j0 + jc + jj) * CR;  // uniform row
#pragma unroll
            for (int r = 0; r < CR; ++r) o[r] += p * vr[r];
        }
        m = mn;
    }

    float* Ob = Opart + (size_t)(s * BATCH + b) * CR * NPOS + n;
#pragma unroll
    for (int r = 0; r < CR; ++r) Ob[(size_t)r * NPOS] = o[r];
    Mpart[(size_t)(s * BATCH + b) * NPOS + n] = m;
    Lpart[(size_t)(s * BATCH + b) * NPOS + n] = l;
}

// ---------------------------------------------------------------------------
// Kernel 3: merge key-splits (log-sum-exp combine) + output projection + residual.
// Block = 256 threads covers 64 positions; wave g handles c in [64g, 64g+64).
// ---------------------------------------------------------------------------
__global__ __launch_bounds__(256) void out_kernel(
    const float* __restrict__ Opart, const float* __restrict__ Mpart,
    const float* __restrict__ Lpart, const float* __restrict__ ow,
    const float* __restrict__ x, float* __restrict__ y, int S)
{
    __shared__ float wsplit[16 * 64];
    __shared__ float invl[64];
    __shared__ float olds[64 * 33];   // +1 pad -> 2-way (free) bank aliasing

    const int b  = blockIdx.y;
    const int nl = threadIdx.x & 63;
    const int n  = blockIdx.x * 64 + nl;
    const int g  = __builtin_amdgcn_readfirstlane(threadIdx.x >> 6); // 0..3

    if (g == 0) {
        float mg = -1e30f;
        for (int s = 0; s < S; ++s)
            mg = fmaxf(mg, Mpart[(size_t)(s * BATCH + b) * NPOS + n]);
        float lg = 0.f;
        for (int s = 0; s < S; ++s) {
            float ms = Mpart[(size_t)(s * BATCH + b) * NPOS + n];
            float w  = __builtin_amdgcn_exp2f((ms - mg) * LOG2E);
            wsplit[s * 64 + nl] = w;
            lg += w * Lpart[(size_t)(s * BATCH + b) * NPOS + n];
        }
        invl[nl] = 1.f / lg;
    }
    __syncthreads();

#pragma unroll
    for (int i = 0; i < 8; ++i) {
        int r = g * 8 + i;
        float acc = 0.f;
        for (int s = 0; s < S; ++s)
            acc += wsplit[s * 64 + nl] *
                   Opart[((size_t)(s * BATCH + b) * CR + r) * NPOS + n];
        olds[nl * 33 + r] = acc * invl[nl];
    }
    __syncthreads();

    float oreg[CR];
#pragma unroll
    for (int r = 0; r < CR; ++r) oreg[r] = olds[nl * 33 + r];

    const float* xb = x + (size_t)b * CIN * NPOS + n;
    float*       yb = y + (size_t)b * CIN * NPOS + n;
    for (int cc = 0; cc < 64; ++cc) {
        int c = g * 64 + cc;                      // wave-uniform
        float acc = xb[(size_t)c * NPOS];
#pragma unroll
        for (int r = 0; r < CR; ++r) acc += ow[c * CR + r] * oreg[r];
        yb[(size_t)c * NPOS] = acc;
    }
}

// ---------------------------------------------------------------------------
extern "C" void kernel_launch(void* const* d_in, const int* in_sizes, int n_in,
                              void* d_out, int out_size, void* d_ws, size_t ws_size,
                              hipStream_t stream)
{
    const float* x  = (const float*)d_in[0];
    const float* qw = (const float*)d_in[1];
    const float* kw = (const float*)d_in[2];
    const float* vw = (const float*)d_in[3];
    const float* ow = (const float*)d_in[4];
    float* out = (float*)d_out;

    const size_t qkvN = (size_t)BATCH * CR * NPOS;  // 401,408 floats
    int S = 16;                                      // key splits (N % S == 0)
    while (S > 1) {
        size_t need = (3 * qkvN + (size_t)S * qkvN +
                       2 * (size_t)S * BATCH * NPOS) * sizeof(float);
        if (need <= ws_size) break;
        S >>= 1;
    }
    float* Q  = (float*)d_ws;
    float* K  = Q + qkvN;
    float* V  = K + qkvN;
    float* Op = V + qkvN;
    float* Mp = Op + (size_t)S * qkvN;
    float* Lp = Mp + (size_t)S * BATCH * NPOS;
    const int kps = NPOS / S;

    qkv_kernel<<<dim3(NT, BATCH), 256, 0, stream>>>(x, qw, kw, vw, Q, K, V);
    attn_kernel<<<dim3(NT, S, BATCH), 64, 0, stream>>>(Q, K, V, Op, Mp, Lp, kps);
    out_kernel<<<dim3(NT, BATCH), 256, 0, stream>>>(Op, Mp, Lp, ow, x, out, S);
}

// Round 2
// 353.154 us; speedup vs baseline: 1.1976x; 1.1976x over previous
//
#include <hip/hip_runtime.h>
#include <hip/hip_bf16.h>

#define NPOS 6272          // 8*28*28
#define NT   98            // NPOS/64
#define CIN  256
#define CR   32
#define BATCH 2
// QSCALE * log2(e): scores come out in log2 units -> softmax uses raw exp2
#define QS2  0.25503371989518595f

// ---------------------------------------------------------------------------
// Kernel 1: Q/K/V projections. gridDim.z picks the matrix (0=Q,1=K,2=V).
// Q layout [B][32][N]  (coalesced per-lane column reads in attention)
// K,V layout [B][N][32] (contiguous 128B per key row -> uniform scalar loads)
// Block = 256 threads = 4 waves; wave g handles r in [8g, 8g+8).
// ---------------------------------------------------------------------------
__global__ __launch_bounds__(256) void qkv_kernel(
    const float* __restrict__ x, const float* __restrict__ qw,
    const float* __restrict__ kw, const float* __restrict__ vw,
    float* __restrict__ Q, float* __restrict__ K, float* __restrict__ V)
{
    const int b  = blockIdx.y;
    const int z  = blockIdx.z;
    const int nl = threadIdx.x & 63;
    const int n  = blockIdx.x * 64 + nl;
    const int g  = __builtin_amdgcn_readfirstlane(threadIdx.x >> 6); // 0..3
    const float* w  = (z == 0) ? qw : (z == 1) ? kw : vw;
    const float* xb = x + (size_t)b * CIN * NPOS + n;

    float acc[8];
#pragma unroll
    for (int i = 0; i < 8; ++i) acc[i] = 0.f;

    for (int c = 0; c < CIN; c += 2) {           // 2-deep to pipeline loads
        float xv0 = xb[(size_t)c * NPOS];
        float xv1 = xb[(size_t)(c + 1) * NPOS];
#pragma unroll
        for (int i = 0; i < 8; ++i) {
            int r = g * 8 + i;                   // wave-uniform -> scalar loads
            acc[i] += w[r * CIN + c] * xv0;
            acc[i] += w[r * CIN + c + 1] * xv1;
        }
    }
    if (z == 0) {
#pragma unroll
        for (int i = 0; i < 8; ++i)
            Q[((size_t)b * CR + g * 8 + i) * NPOS + n] = acc[i] * QS2;
    } else {
        float* dst = (z == 1) ? K : V;
#pragma unroll
        for (int i = 0; i < 8; ++i)
            dst[((size_t)b * NPOS + n) * CR + g * 8 + i] = acc[i];
    }
}

// ---------------------------------------------------------------------------
// Kernel 2: flash attention with key-split (scores already in log2 units).
// 1 block = 1 wave = 64 queries; blockIdx.y = key split s; blockIdx.z = batch.
// Partial (m, l fp32; o[32] bf16) per split to workspace.
// ---------------------------------------------------------------------------
__global__ __launch_bounds__(64) void attn_kernel(
    const float* __restrict__ Q, const float* __restrict__ K,
    const float* __restrict__ V, __hip_bfloat16* __restrict__ Opart,
    float* __restrict__ Mpart, float* __restrict__ Lpart, int kps)
{
    const int b = blockIdx.z;
    const int s = blockIdx.y;
    const int n = blockIdx.x * 64 + threadIdx.x;

    const float* Qb = Q + (size_t)b * CR * NPOS + n;
    const float* Kb = K + (size_t)b * NPOS * CR;
    const float* Vb = V + (size_t)b * NPOS * CR;

    float q[CR];
#pragma unroll
    for (int r = 0; r < CR; ++r) q[r] = Qb[(size_t)r * NPOS];
    float o[CR];
#pragma unroll
    for (int r = 0; r < CR; ++r) o[r] = 0.f;
    float m = -1e30f, l = 0.f;

    const int j0 = s * kps;
    for (int jc = 0; jc < kps; jc += 8) {        // kps % 8 == 0 guaranteed
        float sc[8];
#pragma unroll
        for (int jj = 0; jj < 8; ++jj) {
            const float* kr = Kb + (size_t)(j0 + jc + jj) * CR;  // uniform row
            float a0 = 0.f, a1 = 0.f, a2 = 0.f, a3 = 0.f;
#pragma unroll
            for (int r = 0; r < CR; r += 4) {
                a0 += q[r]     * kr[r];
                a1 += q[r + 1] * kr[r + 1];
                a2 += q[r + 2] * kr[r + 2];
                a3 += q[r + 3] * kr[r + 3];
            }
            sc[jj] = (a0 + a1) + (a2 + a3);
        }
        float cm = sc[0];
#pragma unroll
        for (int jj = 1; jj < 8; ++jj) cm = fmaxf(cm, sc[jj]);
        float mn    = fmaxf(m, cm);
        float alpha = __builtin_amdgcn_exp2f(m - mn);
        l *= alpha;
#pragma unroll
        for (int r = 0; r < CR; ++r) o[r] *= alpha;
#pragma unroll
        for (int jj = 0; jj < 8; ++jj) {
            float p = __builtin_amdgcn_exp2f(sc[jj] - mn);
            l += p;
            const float* vr = Vb + (size_t)(j0 + jc + jj) * CR;  // uniform row
#pragma unroll
            for (int r = 0; r < CR; ++r) o[r] += p * vr[r];
        }
        m = mn;
    }

    __hip_bfloat16* Ob = Opart + (size_t)(s * BATCH + b) * CR * NPOS + n;
#pragma unroll
    for (int r = 0; r < CR; ++r) Ob[(size_t)r * NPOS] = __float2bfloat16(o[r]);
    Mpart[(size_t)(s * BATCH + b) * NPOS + n] = m;
    Lpart[(size_t)(s * BATCH + b) * NPOS + n] = l;
}

// ---------------------------------------------------------------------------
// Kernel 3: merge key-splits (log-sum-exp combine) -> Omrg [B][32][N] fp32.
// grid (NT, B, 2); block 256 = 4 waves; wave g handles r = z*16 + g*4 + i.
// Each wave computes the split weights redundantly (no LDS / barriers).
// ---------------------------------------------------------------------------
__global__ __launch_bounds__(256) void merge_kernel(
    const __hip_bfloat16* __restrict__ Opart, const float* __restrict__ Mpart,
    const float* __restrict__ Lpart, float* __restrict__ Omrg, int S)
{
    const int b  = blockIdx.y;
    const int z  = blockIdx.z;
    const int nl = threadIdx.x & 63;
    const int n  = blockIdx.x * 64 + nl;
    const int g  = __builtin_amdgcn_readfirstlane(threadIdx.x >> 6);
    const int r0 = z * 16 + g * 4;

    float mg = -1e30f;
    for (int s = 0; s < S; ++s)
        mg = fmaxf(mg, Mpart[(size_t)(s * BATCH + b) * NPOS + n]);
    float lg = 0.f;
    float acc[4];
#pragma unroll
    for (int i = 0; i < 4; ++i) acc[i] = 0.f;
    for (int s = 0; s < S; ++s) {
        float ms = Mpart[(size_t)(s * BATCH + b) * NPOS + n];
        float w  = __builtin_amdgcn_exp2f(ms - mg);
        lg += w * Lpart[(size_t)(s * BATCH + b) * NPOS + n];
        const __hip_bfloat16* Ob =
            Opart + (size_t)(s * BATCH + b) * CR * NPOS + n;
#pragma unroll
        for (int i = 0; i < 4; ++i)
            acc[i] += w * __bfloat162float(Ob[(size_t)(r0 + i) * NPOS]);
    }
    float inv = 1.f / lg;
#pragma unroll
    for (int i = 0; i < 4; ++i)
        Omrg[((size_t)b * CR + r0 + i) * NPOS + n] = acc[i] * inv;
}

// ---------------------------------------------------------------------------
// Kernel 4: output projection + residual.
// grid (NT, B, 4); block 256 = 4 waves; wave g handles c in [z*64+16g, +16).
// ---------------------------------------------------------------------------
__global__ __launch_bounds__(256) void proj_kernel(
    const float* __restrict__ Omrg, const float* __restrict__ ow,
    const float* __restrict__ x, float* __restrict__ y)
{
    const int b  = blockIdx.y;
    const int z  = blockIdx.z;
    const int nl = threadIdx.x & 63;
    const int n  = blockIdx.x * 64 + nl;
    const int g  = __builtin_amdgcn_readfirstlane(threadIdx.x >> 6);

    float o[CR];
#pragma unroll
    for (int r = 0; r < CR; ++r)
        o[r] = Omrg[((size_t)b * CR + r) * NPOS + n];

    const float* xb = x + (size_t)b * CIN * NPOS + n;
    float*       yb = y + (size_t)b * CIN * NPOS + n;
    const int c0 = z * 64 + g * 16;
    for (int cc = 0; cc < 16; ++cc) {
        int c = c0 + cc;                          // wave-uniform
        float acc = xb[(size_t)c * NPOS];
#pragma unroll
        for (int r = 0; r < CR; ++r) acc += ow[c * CR + r] * o[r];
        yb[(size_t)c * NPOS] = acc;
    }
}

// ---------------------------------------------------------------------------
extern "C" void kernel_launch(void* const* d_in, const int* in_sizes, int n_in,
                              void* d_out, int out_size, void* d_ws, size_t ws_size,
                              hipStream_t stream)
{
    const float* x  = (const float*)d_in[0];
    const float* qw = (const float*)d_in[1];
    const float* kw = (const float*)d_in[2];
    const float* vw = (const float*)d_in[3];
    const float* ow = (const float*)d_in[4];
    float* out = (float*)d_out;

    const size_t qkvN = (size_t)BATCH * CR * NPOS;  // 401,408 elements
    // S candidates keep kps = NPOS/S a multiple of 8 (chunk loop).
    const int s_cand[6] = {28, 14, 7, 4, 2, 1};
    int S = 1;
    for (int i = 0; i < 6; ++i) {
        int Sc = s_cand[i];
        size_t need = (3 * qkvN + qkvN) * sizeof(float)               // Q,K,V,Omrg
                    + (size_t)Sc * qkvN * sizeof(__hip_bfloat16)      // Opart
                    + 2 * (size_t)Sc * BATCH * NPOS * sizeof(float);  // M,L
        if (need <= ws_size) { S = Sc; break; }
    }
    float* Q    = (float*)d_ws;
    float* K    = Q + qkvN;
    float* V    = K + qkvN;
    float* Omrg = V + qkvN;
    __hip_bfloat16* Op = (__hip_bfloat16*)(Omrg + qkvN);
    float* Mp = (float*)(Op + (size_t)S * qkvN);
    float* Lp = Mp + (size_t)S * BATCH * NPOS;
    const int kps = NPOS / S;

    qkv_kernel<<<dim3(NT, BATCH, 3), 256, 0, stream>>>(x, qw, kw, vw, Q, K, V);
    attn_kernel<<<dim3(NT, S, BATCH), 64, 0, stream>>>(Q, K, V, Op, Mp, Lp, kps);
    merge_kernel<<<dim3(NT, BATCH, 2), 256, 0, stream>>>(Op, Mp, Lp, Omrg, S);
    proj_kernel<<<dim3(NT, BATCH, 4), 256, 0, stream>>>(Omrg, ow, x, out);
}